// Round 3
// baseline (2293.527 us; speedup 1.0000x reference)
//
#include <hip/hip_runtime.h>
#include <math.h>

// ---------------------------------------------------------------------------
// Com_CNN_RNN: 2-epoch stacked GRU (T=256, E=512) -> conv1d+maxpool (degenerate
// global max) -> GRU2 (T=2) -> similarity head. Full fp32.
//
// R2: register residency fix. 16 WGs x 512 thr, 16 lanes/group, 96 weight
// floats/thread (pinned via empty asm), both sentences per WG. R1's relaxed
// agent-scope (sc1/LLC) sync: per-WG flag lines, no fences, no RMW.
// ---------------------------------------------------------------------------

__device__ __forceinline__ float sigm(float x) { return 1.f / (1.f + expf(-x)); }

// mode 0: gi precomputed in global [2][T][1536]   (T=256)
// mode 1: gi from xin [2][2][512] with Wih/bih in prologue (T=2)
// mode 2: gi = mscal[s*2+t] * Srow[row] + bih[row] (T=2)
__global__ __launch_bounds__(512, 2) void k_chain3(
    const float* __restrict__ Whh, const float* __restrict__ bhh,
    const float* __restrict__ gi,
    const float* __restrict__ Wih, const float* __restrict__ bih,
    const float* __restrict__ xin,
    const float* __restrict__ mscal, const float* __restrict__ Srow,
    float* __restrict__ xout,            // [2][T][512] or null
    float* __restrict__ finout, long fin_ss,
    float* __restrict__ hstep,           // [T+1][2][512]
    unsigned int* __restrict__ flags,    // [16][16] one 64B line per WG
    int T, int mode)
{
    const int tid  = threadIdx.x;
    const int wgi  = blockIdx.x;         // 0..15
    const int grp  = tid >> 4;           // 0..31
    const int lane = tid & 15;           // 16 lanes per group
    const int j    = wgi * 32 + grp;     // h row 0..511
    const int colbase = lane * 32;       // 32 k-columns per lane

    // pad 4 words per 32: index map p(k) = k + (k>>5)*4
    __shared__ float hlds[1152];

    // ---- register-resident weights: rows {j,512+j,1024+j} x 32 cols ----
    float wreg[3][32];
#pragma unroll
    for (int q = 0; q < 3; ++q) {
        const float* src = Whh + (size_t)(q * 512 + j) * 512 + colbase;
#pragma unroll
        for (int c4 = 0; c4 < 8; ++c4) {
            float4 v = *(const float4*)(src + c4 * 4);
            wreg[q][c4 * 4 + 0] = v.x; wreg[q][c4 * 4 + 1] = v.y;
            wreg[q][c4 * 4 + 2] = v.z; wreg[q][c4 * 4 + 3] = v.w;
        }
    }
    // pin: force materialization into VGPRs; blocks remat/sinking into loop
#pragma unroll
    for (int q = 0; q < 3; ++q)
#pragma unroll
        for (int c = 0; c < 32; ++c)
            asm volatile("" : "+v"(wreg[q][c]));

    float bhh_q[3];
#pragma unroll
    for (int q = 0; q < 3; ++q) bhh_q[q] = bhh[q * 512 + j];
    float bih_q[3] = {0.f, 0.f, 0.f};
    if (mode != 0) {
#pragma unroll
        for (int q = 0; q < 3; ++q) bih_q[q] = bih[q * 512 + j];
    }

    // ---- prologue gi for the T==2 modes: gp0 = step0, gp1 = step1 ----
    float gp0[3][2], gp1[3][2];
    if (mode == 1) {
#pragma unroll
        for (int t = 0; t < 2; ++t) {
            float xr[2][32];
#pragma unroll
            for (int s = 0; s < 2; ++s) {
                const float* xp = xin + (size_t)s * 1024 + (size_t)t * 512 + colbase;
#pragma unroll
                for (int c4 = 0; c4 < 8; ++c4) {
                    float4 v = *(const float4*)(xp + c4 * 4);
                    xr[s][c4*4+0] = v.x; xr[s][c4*4+1] = v.y;
                    xr[s][c4*4+2] = v.z; xr[s][c4*4+3] = v.w;
                }
            }
#pragma unroll
            for (int q = 0; q < 3; ++q) {
                const float* wp = Wih + (size_t)(q * 512 + j) * 512 + colbase;
                float a0 = 0.f, a1 = 0.f;
#pragma unroll
                for (int c4 = 0; c4 < 8; ++c4) {
                    float4 w4 = *(const float4*)(wp + c4 * 4);
                    a0 += w4.x * xr[0][c4*4+0] + w4.y * xr[0][c4*4+1]
                        + w4.z * xr[0][c4*4+2] + w4.w * xr[0][c4*4+3];
                    a1 += w4.x * xr[1][c4*4+0] + w4.y * xr[1][c4*4+1]
                        + w4.z * xr[1][c4*4+2] + w4.w * xr[1][c4*4+3];
                }
#pragma unroll
                for (int off = 8; off >= 1; off >>= 1) {
                    a0 += __shfl_xor(a0, off, 64);
                    a1 += __shfl_xor(a1, off, 64);
                }
                if (t == 0) { gp0[q][0] = a0 + bih_q[q]; gp0[q][1] = a1 + bih_q[q]; }
                else        { gp1[q][0] = a0 + bih_q[q]; gp1[q][1] = a1 + bih_q[q]; }
            }
        }
    } else if (mode == 2) {
#pragma unroll
        for (int q = 0; q < 3; ++q) {
            float Sq = Srow[q * 512 + j];
#pragma unroll
            for (int s = 0; s < 2; ++s) {
                gp0[q][s] = mscal[s * 2 + 0] * Sq + bih_q[q];
                gp1[q][s] = mscal[s * 2 + 1] * Sq + bih_q[q];
            }
        }
    }

    unsigned int* myflag = flags + (size_t)wgi * 16;

    // ---- step loop ----
    for (int t = 0; t < T; ++t) {
        // gi for this step (issued before the poll so latency hides)
        float g0[3][2];
        if (mode == 0) {
#pragma unroll
            for (int q = 0; q < 3; ++q)
#pragma unroll
                for (int s = 0; s < 2; ++s)
                    g0[q][s] = gi[(size_t)(s * T + t) * 1536 + q * 512 + j];
        } else {
#pragma unroll
            for (int q = 0; q < 3; ++q)
#pragma unroll
                for (int s = 0; s < 2; ++s)
                    g0[q][s] = (t == 0) ? gp0[q][s] : gp1[q][s];
        }

        if (t > 0) {
            // wait for all 16 WGs to have published h_t
            if (tid < 16) {
                const unsigned int* fp = flags + (size_t)tid * 16;
                while (__hip_atomic_load(fp, __ATOMIC_RELAXED,
                                         __HIP_MEMORY_SCOPE_AGENT) < (unsigned)t)
                    __builtin_amdgcn_s_sleep(1);
            }
            __syncthreads();
            // stage h_t (both sentences, 1024 floats) via 8B LLC loads
            if (tid < 256) {
                const unsigned long long* src =
                    (const unsigned long long*)(hstep + (size_t)t * 1024) + tid * 2;
                unsigned long long d0 = __hip_atomic_load(src + 0, __ATOMIC_RELAXED,
                                                          __HIP_MEMORY_SCOPE_AGENT);
                unsigned long long d1 = __hip_atomic_load(src + 1, __ATOMIC_RELAXED,
                                                          __HIP_MEMORY_SCOPE_AGENT);
                union { unsigned long long u; float2 f; } c0, c1;
                c0.u = d0; c1.u = d1;
                const int i = tid * 4;
                const int pb = i + ((i >> 5) << 2);
                float4 w; w.x = c0.f.x; w.y = c0.f.y; w.z = c1.f.x; w.w = c1.f.y;
                *(float4*)&hlds[pb] = w;
            }
            __syncthreads();
        }

        // gh partials: 3 gates x 2 sentences over this lane's 32 columns
        float accq[3][2];
#pragma unroll
        for (int q = 0; q < 3; ++q) { accq[q][0] = 0.f; accq[q][1] = 0.f; }
        float hold[2] = {0.f, 0.f};
        if (t > 0) {
#pragma unroll
            for (int s = 0; s < 2; ++s) {
                const int k = s * 512 + j;
                hold[s] = hlds[k + ((k >> 5) << 2)];
                const int kb = s * 512 + colbase;
                const int pb = kb + ((kb >> 5) << 2);
#pragma unroll
                for (int c4 = 0; c4 < 8; ++c4) {
                    float4 hv = *(const float4*)&hlds[pb + c4 * 4];
#pragma unroll
                    for (int q = 0; q < 3; ++q) {
                        accq[q][s] += wreg[q][c4*4+0] * hv.x + wreg[q][c4*4+1] * hv.y
                                    + wreg[q][c4*4+2] * hv.z + wreg[q][c4*4+3] * hv.w;
                    }
                }
            }
#pragma unroll
            for (int q = 0; q < 3; ++q)
#pragma unroll
                for (int s = 0; s < 2; ++s) {
                    float v = accq[q][s];
                    v += __shfl_xor(v, 8, 64);
                    v += __shfl_xor(v, 4, 64);
                    v += __shfl_xor(v, 2, 64);
                    v += __shfl_xor(v, 1, 64);
                    accq[q][s] = v;
                }
        }

        float hn[2];
#pragma unroll
        for (int s = 0; s < 2; ++s) {
            const float rr = sigm(g0[0][s] + accq[0][s] + bhh_q[0]);
            const float zz = sigm(g0[1][s] + accq[1][s] + bhh_q[1]);
            const float nn = tanhf(g0[2][s] + rr * (accq[2][s] + bhh_q[2]));
            hn[s] = (1.f - zz) * nn + zz * hold[s];
        }

        if (lane == 0) {
#pragma unroll
            for (int s = 0; s < 2; ++s) {
                __hip_atomic_store(hstep + (size_t)(t + 1) * 1024 + s * 512 + j, hn[s],
                                   __ATOMIC_RELAXED, __HIP_MEMORY_SCOPE_AGENT);
                if (xout != nullptr)
                    xout[((size_t)s * T + t) * 512 + j] = hn[s];
                if (finout != nullptr && t == T - 1)
                    finout[(size_t)s * fin_ss + j] = hn[s];
            }
        }
        __builtin_amdgcn_s_waitcnt(0);   // this wave's h stores are in the LLC
        __syncthreads();                 // -> all waves' stores are
        if (tid == 0)
            __hip_atomic_store(myflag, (unsigned)(t + 1),
                               __ATOMIC_RELAXED, __HIP_MEMORY_SCOPE_AGENT);
    }
}

// ---------------------------------------------------------------------------
// gi GEMM: out[m][n] = sum_k A[m][k] * W[n][k] + bias[n]; M=512, N=1536, K=512.
// ---------------------------------------------------------------------------
__global__ __launch_bounds__(256, 2) void k_gemm_gi(
    const float* __restrict__ W, const float* __restrict__ bias,
    const float* __restrict__ emb, const int* __restrict__ sentA,
    const int* __restrict__ sentB, const float* __restrict__ xsrc,
    float* __restrict__ out)
{
    __shared__ float At[32][68];
    __shared__ float Wt[32][68];
    const int tid = threadIdx.x;
    const int n0 = blockIdx.x * 64;
    const int m0 = blockIdx.y * 64;
    const int lrow = tid >> 3, lc4 = tid & 7;

    const float *ar0, *ar1;
    {
        const int ma = m0 + lrow, mb = ma + 32;
        if (emb != nullptr) {
            const int ia = (ma < 256) ? sentA[ma & 255] : sentB[ma & 255];
            const int ib = (mb < 256) ? sentA[mb & 255] : sentB[mb & 255];
            ar0 = emb + (size_t)ia * 512;
            ar1 = emb + (size_t)ib * 512;
        } else {
            ar0 = xsrc + (size_t)ma * 512;
            ar1 = xsrc + (size_t)mb * 512;
        }
    }
    const float* wr0 = W + (size_t)(n0 + lrow) * 512;
    const float* wr1 = wr0 + (size_t)32 * 512;

    const int ty = tid >> 4, tx = tid & 15;
    float acc[4][4];
#pragma unroll
    for (int i = 0; i < 4; ++i)
#pragma unroll
        for (int jj = 0; jj < 4; ++jj) acc[i][jj] = 0.f;

    for (int kk = 0; kk < 512; kk += 32) {
        float4 a0 = *(const float4*)(ar0 + kk + lc4 * 4);
        float4 a1 = *(const float4*)(ar1 + kk + lc4 * 4);
        float4 w0 = *(const float4*)(wr0 + kk + lc4 * 4);
        float4 w1 = *(const float4*)(wr1 + kk + lc4 * 4);
        __syncthreads();
        const int kb = lc4 * 4;
        At[kb+0][lrow] = a0.x; At[kb+1][lrow] = a0.y; At[kb+2][lrow] = a0.z; At[kb+3][lrow] = a0.w;
        At[kb+0][lrow+32] = a1.x; At[kb+1][lrow+32] = a1.y; At[kb+2][lrow+32] = a1.z; At[kb+3][lrow+32] = a1.w;
        Wt[kb+0][lrow] = w0.x; Wt[kb+1][lrow] = w0.y; Wt[kb+2][lrow] = w0.z; Wt[kb+3][lrow] = w0.w;
        Wt[kb+0][lrow+32] = w1.x; Wt[kb+1][lrow+32] = w1.y; Wt[kb+2][lrow+32] = w1.z; Wt[kb+3][lrow+32] = w1.w;
        __syncthreads();
#pragma unroll
        for (int k = 0; k < 32; ++k) {
            float4 av = *(const float4*)&At[k][ty * 4];
            float4 wv = *(const float4*)&Wt[k][tx * 4];
            acc[0][0] += av.x * wv.x; acc[0][1] += av.x * wv.y; acc[0][2] += av.x * wv.z; acc[0][3] += av.x * wv.w;
            acc[1][0] += av.y * wv.x; acc[1][1] += av.y * wv.y; acc[1][2] += av.y * wv.z; acc[1][3] += av.y * wv.w;
            acc[2][0] += av.z * wv.x; acc[2][1] += av.z * wv.y; acc[2][2] += av.z * wv.z; acc[2][3] += av.z * wv.w;
            acc[3][0] += av.w * wv.x; acc[3][1] += av.w * wv.y; acc[3][2] += av.w * wv.z; acc[3][3] += av.w * wv.w;
        }
    }
    float4 b4 = *(const float4*)(bias + n0 + tx * 4);
#pragma unroll
    for (int i = 0; i < 4; ++i) {
        const int m = m0 + ty * 4 + i;
        float4 r;
        r.x = acc[i][0] + b4.x; r.y = acc[i][1] + b4.y;
        r.z = acc[i][2] + b4.z; r.w = acc[i][3] + b4.w;
        *(float4*)(out + (size_t)m * 1536 + n0 + tx * 4) = r;
    }
}

// ---------------------------------------------------------------------------
__global__ __launch_bounds__(256) void k_init(
    const float* __restrict__ Wih2, float* __restrict__ Srow,
    unsigned int* __restrict__ flags)
{
    const int g = blockIdx.x * 256 + threadIdx.x;   // 0..2047
    if (g < 1536) {
        float s = 0.f;
        for (int k = 0; k < 128; ++k) s += Wih2[(size_t)g * 128 + k];
        Srow[g] = s;
    }
    if (g < 5 * 256) flags[g] = 0u;
}

// ---------------------------------------------------------------------------
__global__ __launch_bounds__(256) void k_convpool(
    const float* __restrict__ x0, const float* __restrict__ x1,
    const float* __restrict__ cw, const float* __restrict__ cb,
    float* __restrict__ Mmax)
{
    __shared__ float hh[2][512];
    __shared__ float wsh[2][512];
    __shared__ float red[4];
    const int s = blockIdx.x >> 1, o = blockIdx.x & 1;
    const int tid = threadIdx.x;
    for (int i = tid; i < 512; i += 256) {
        hh[0][i] = x0[(size_t)(s * 2 + 1) * 512 + i];
        hh[1][i] = x1[(size_t)(s * 2 + 1) * 512 + i];
        wsh[0][i] = cw[(size_t)(o * 2 + 0) * 512 + i];
        wsh[1][i] = cw[(size_t)(o * 2 + 1) * 512 + i];
    }
    __syncthreads();
    const int p = tid;
    float acc = cb[o];
    const int base = 2 * p - 255;
#pragma unroll 1
    for (int ch = 0; ch < 2; ++ch) {
        for (int k = 0; k < 512; ++k) {
            const int pos = base + k;
            if ((unsigned)pos < 512u) acc += hh[ch][pos] * wsh[ch][k];
        }
    }
    float m = acc;
#pragma unroll
    for (int off = 32; off >= 1; off >>= 1) m = fmaxf(m, __shfl_xor(m, off, 64));
    if ((tid & 63) == 0) red[tid >> 6] = m;
    __syncthreads();
    if (tid == 0)
        Mmax[blockIdx.x] = fmaxf(fmaxf(red[0], red[1]), fmaxf(red[2], red[3]));
}

// ---------------------------------------------------------------------------
__global__ __launch_bounds__(256) void k_head(
    const float* __restrict__ xr2,
    const float* __restrict__ WA, const float* __restrict__ WB,
    const float* __restrict__ b_bi, const float* __restrict__ Wlin,
    const float* __restrict__ blin, float* __restrict__ outp)
{
    __shared__ float hA[512], hB[512];
    __shared__ float red[4];
    const int tid = threadIdx.x;
    for (int i = tid; i < 512; i += 256) {
        hA[i] = xr2[512 + i];
        hB[i] = xr2[3 * 512 + i];
    }
    __syncthreads();
    float acc = b_bi[tid];
    for (int jj = 0; jj < 512; ++jj) {
        const float a = hA[jj], b = hB[jj];
        acc += (a * b) * WA[jj * 256 + tid] + fabsf(a - b) * WB[jj * 256 + tid];
    }
    float v = tanhf(acc) * Wlin[tid];
#pragma unroll
    for (int off = 32; off >= 1; off >>= 1) v += __shfl_xor(v, off, 64);
    if ((tid & 63) == 0) red[tid >> 6] = v;
    __syncthreads();
    if (tid == 0) {
        const float ssum = red[0] + red[1] + red[2] + red[3] + blin[0];
        outp[0] = 1.f / (1.f + expf(-ssum));
    }
}

// ---------------------------------------------------------------------------
extern "C" void kernel_launch(void* const* d_in, const int* in_sizes, int n_in,
                              void* d_out, int out_size, void* d_ws, size_t ws_size,
                              hipStream_t stream)
{
    const int*   sentA = (const int*)d_in[0];
    const int*   sentB = (const int*)d_in[1];
    const float* emb   = (const float*)d_in[2];
    const float* Wih1  = (const float*)d_in[3];   // [2][1536][512]
    const float* Whh1  = (const float*)d_in[4];   // [2][1536][512]
    const float* bih1  = (const float*)d_in[5];   // [2][1536]
    const float* bhh1  = (const float*)d_in[6];   // [2][1536]
    const float* convw = (const float*)d_in[7];   // [2][2][512]
    const float* convb = (const float*)d_in[8];   // [2]
    const float* Wih2  = (const float*)d_in[9];   // [1536][128]
    const float* Whh2  = (const float*)d_in[10];  // [1536][512]
    const float* bih2  = (const float*)d_in[11];  // [1536]
    const float* bhh2  = (const float*)d_in[12];  // [1536]
    const float* WA    = (const float*)d_in[13];  // [512][256]
    const float* WB    = (const float*)d_in[14];  // [512][256]
    const float* b_bi  = (const float*)d_in[15];  // [256]
    const float* Wlin  = (const float*)d_in[16];  // [1][256]
    const float* blin  = (const float*)d_in[17];  // [1]

    float* ws = (float*)d_ws;
    size_t off = 0;
    float* gi_buf = ws + off; off += 786432;          // [2][256][1536]
    float* xout0  = ws + off; off += 262144;          // e1 L0 outputs [2][256][512]
    float* e2x    = ws + off; off += 2048;            // epoch2 input [2][2][512]
    float* xo20   = ws + off; off += 2048;
    float* xo21   = ws + off; off += 2048;
    float* xr2b   = ws + off; off += 2048;
    float* Mmax   = ws + off; off += 16;
    float* Srow   = ws + off; off += 1536;
    float* hs0    = ws + off; off += 257 * 1024;      // hstep chain0
    float* hs1    = ws + off; off += 257 * 1024;      // hstep chain1
    float* hs2    = ws + off; off += 3 * 1024;
    float* hs3    = ws + off; off += 3 * 1024;
    float* hs4    = ws + off; off += 3 * 1024;
    unsigned int* flags = (unsigned int*)(ws + off); off += 5 * 256;

    const size_t WSTRIDE = (size_t)1536 * 512;

    k_init<<<8, 256, 0, stream>>>(Wih2, Srow, flags);

    // epoch 1, layer 0
    k_gemm_gi<<<dim3(24, 8), 256, 0, stream>>>(Wih1, bih1, emb, sentA, sentB, nullptr, gi_buf);
    k_chain3<<<16, 512, 0, stream>>>(Whh1, bhh1, gi_buf,
                                     nullptr, nullptr, nullptr, nullptr, nullptr,
                                     xout0, e2x, 1024, hs0, flags + 0 * 256, 256, 0);
    // epoch 1, layer 1
    k_gemm_gi<<<dim3(24, 8), 256, 0, stream>>>(Wih1 + WSTRIDE, bih1 + 1536,
                                               nullptr, nullptr, nullptr, xout0, gi_buf);
    k_chain3<<<16, 512, 0, stream>>>(Whh1 + WSTRIDE, bhh1 + 1536, gi_buf,
                                     nullptr, nullptr, nullptr, nullptr, nullptr,
                                     nullptr, e2x + 512, 1024, hs1, flags + 1 * 256, 256, 0);
    // epoch 2, layer 0 (T=2)
    k_chain3<<<16, 512, 0, stream>>>(Whh1, bhh1, nullptr,
                                     Wih1, bih1, e2x, nullptr, nullptr,
                                     xo20, nullptr, 0, hs2, flags + 2 * 256, 2, 1);
    // epoch 2, layer 1 (T=2)
    k_chain3<<<16, 512, 0, stream>>>(Whh1 + WSTRIDE, bhh1 + 1536, nullptr,
                                     Wih1 + WSTRIDE, bih1 + 1536, xo20, nullptr, nullptr,
                                     xo21, nullptr, 0, hs3, flags + 3 * 256, 2, 1);
    // conv + degenerate max pool
    k_convpool<<<4, 256, 0, stream>>>(xo20, xo21, convw, convb, Mmax);
    // rnn_second (T=2)
    k_chain3<<<16, 512, 0, stream>>>(Whh2, bhh2, nullptr,
                                     nullptr, bih2, nullptr, Mmax, Srow,
                                     xr2b, nullptr, 0, hs4, flags + 4 * 256, 2, 2);
    // similarity head
    k_head<<<1, 256, 0, stream>>>(xr2b, WA, WB, b_bi, Wlin, blin, (float*)d_out);
}

// Round 4
// 1982.388 us; speedup vs baseline: 1.1570x; 1.1570x over previous
//
#include <hip/hip_runtime.h>
#include <math.h>

// ---------------------------------------------------------------------------
// Com_CNN_RNN: 2-epoch stacked GRU (T=256, E=512) -> conv1d+maxpool (degenerate
// global max) -> GRU2 (T=2) -> similarity head. Full fp32.
//
// R3: residency by shrinking footprint. 32 WGs x 512 thr per chain; each WG
// owns 16 h-rows (x3 gates), 32 lanes/row, 16 cols/lane = 48 weight floats
// per thread -> total live ~110 VGPRs, under the 128 cap the allocator picks.
// Relaxed agent-scope (sc1/LLC) sync: per-WG flag lines, no fences, no RMW.
// ---------------------------------------------------------------------------

__device__ __forceinline__ float sigm(float x) { return 1.f / (1.f + expf(-x)); }

// LDS index map: p(k) = k + (k>>4)*4  (pad 4 words per 16; keeps float4 align)
#define LDSP(k) ((k) + (((k) >> 4) << 2))

// mode 0: gi precomputed in global [2][T][1536]   (T=256)
// mode 1: gi from xin [2][2][512] with Wih/bih in prologue (T=2)
// mode 2: gi = mscal[s*2+t] * Srow[row] + bih[row] (T=2)
__global__ __launch_bounds__(512, 2) void k_chain4(
    const float* __restrict__ Whh, const float* __restrict__ bhh,
    const float* __restrict__ gi,
    const float* __restrict__ Wih, const float* __restrict__ bih,
    const float* __restrict__ xin,
    const float* __restrict__ mscal, const float* __restrict__ Srow,
    float* __restrict__ xout,            // [2][T][512] or null
    float* __restrict__ finout, long fin_ss,
    float* __restrict__ hstep,           // [T+1][2][512]
    unsigned int* __restrict__ flags,    // [32][16] one 64B line per WG
    int T, int mode)
{
    const int tid  = threadIdx.x;
    const int wgi  = blockIdx.x;         // 0..31
    const int grp  = tid >> 5;           // 0..15
    const int lane = tid & 31;           // 32 lanes per row
    const int j    = wgi * 16 + grp;     // h row 0..511
    const int colbase = lane * 16;       // 16 k-columns per lane

    __shared__ float hlds[1280];

    // ---- register-resident weights: rows {j,512+j,1024+j} x 16 cols ----
    float wreg[3][16];
#pragma unroll
    for (int q = 0; q < 3; ++q) {
        const float* src = Whh + (size_t)(q * 512 + j) * 512 + colbase;
#pragma unroll
        for (int c4 = 0; c4 < 4; ++c4) {
            float4 v = *(const float4*)(src + c4 * 4);
            wreg[q][c4 * 4 + 0] = v.x; wreg[q][c4 * 4 + 1] = v.y;
            wreg[q][c4 * 4 + 2] = v.z; wreg[q][c4 * 4 + 3] = v.w;
        }
    }
    // pin: force materialization; blocks remat into the loop (fits the cap now)
#pragma unroll
    for (int q = 0; q < 3; ++q)
#pragma unroll
        for (int c = 0; c < 16; ++c)
            asm volatile("" : "+v"(wreg[q][c]));

    float bhh_q[3];
#pragma unroll
    for (int q = 0; q < 3; ++q) bhh_q[q] = bhh[q * 512 + j];
    float bih_q[3] = {0.f, 0.f, 0.f};
    if (mode != 0) {
#pragma unroll
        for (int q = 0; q < 3; ++q) bih_q[q] = bih[q * 512 + j];
    }

    // ---- prologue gi for the T==2 modes: gp0 = step0, gp1 = step1 ----
    float gp0[3][2], gp1[3][2];
    if (mode == 1) {
#pragma unroll
        for (int t = 0; t < 2; ++t) {
#pragma unroll
            for (int s = 0; s < 2; ++s) {
                float xr[16];
                const float* xp = xin + (size_t)s * 1024 + (size_t)t * 512 + colbase;
#pragma unroll
                for (int c4 = 0; c4 < 4; ++c4) {
                    float4 v = *(const float4*)(xp + c4 * 4);
                    xr[c4*4+0] = v.x; xr[c4*4+1] = v.y;
                    xr[c4*4+2] = v.z; xr[c4*4+3] = v.w;
                }
#pragma unroll
                for (int q = 0; q < 3; ++q) {
                    const float* wp = Wih + (size_t)(q * 512 + j) * 512 + colbase;
                    float a = 0.f;
#pragma unroll
                    for (int c4 = 0; c4 < 4; ++c4) {
                        float4 w4 = *(const float4*)(wp + c4 * 4);
                        a += w4.x * xr[c4*4+0] + w4.y * xr[c4*4+1]
                           + w4.z * xr[c4*4+2] + w4.w * xr[c4*4+3];
                    }
#pragma unroll
                    for (int off = 16; off >= 1; off >>= 1)
                        a += __shfl_xor(a, off, 64);
                    a += bih_q[q];
                    if (t == 0) gp0[q][s] = a; else gp1[q][s] = a;
                }
            }
        }
    } else if (mode == 2) {
#pragma unroll
        for (int q = 0; q < 3; ++q) {
            float Sq = Srow[q * 512 + j];
#pragma unroll
            for (int s = 0; s < 2; ++s) {
                gp0[q][s] = mscal[s * 2 + 0] * Sq + bih_q[q];
                gp1[q][s] = mscal[s * 2 + 1] * Sq + bih_q[q];
            }
        }
    }

    unsigned int* myflag = flags + (size_t)wgi * 16;

    // ---- step loop ----
    for (int t = 0; t < T; ++t) {
        // gi for this step (issued before the poll so latency hides)
        float g0[3][2];
        if (mode == 0) {
#pragma unroll
            for (int q = 0; q < 3; ++q)
#pragma unroll
                for (int s = 0; s < 2; ++s)
                    g0[q][s] = gi[(size_t)(s * T + t) * 1536 + q * 512 + j];
        } else {
#pragma unroll
            for (int q = 0; q < 3; ++q)
#pragma unroll
                for (int s = 0; s < 2; ++s)
                    g0[q][s] = (t == 0) ? gp0[q][s] : gp1[q][s];
        }

        if (t > 0) {
            // wait for all 32 WGs to have published h_t
            if (tid < 32) {
                const unsigned int* fp = flags + (size_t)tid * 16;
                while (__hip_atomic_load(fp, __ATOMIC_RELAXED,
                                         __HIP_MEMORY_SCOPE_AGENT) < (unsigned)t)
                    __builtin_amdgcn_s_sleep(1);
            }
            __syncthreads();
            // stage h_t (both sentences, 1024 floats) via 8B LLC loads
            if (tid < 256) {
                const unsigned long long* src =
                    (const unsigned long long*)(hstep + (size_t)t * 1024) + tid * 2;
                unsigned long long d0 = __hip_atomic_load(src + 0, __ATOMIC_RELAXED,
                                                          __HIP_MEMORY_SCOPE_AGENT);
                unsigned long long d1 = __hip_atomic_load(src + 1, __ATOMIC_RELAXED,
                                                          __HIP_MEMORY_SCOPE_AGENT);
                union { unsigned long long u; float2 f; } c0, c1;
                c0.u = d0; c1.u = d1;
                const int i = tid * 4;           // multiple of 4 -> aligned slot
                float* dst = &hlds[LDSP(i)];
                dst[0] = c0.f.x; dst[1] = c0.f.y; dst[2] = c1.f.x; dst[3] = c1.f.y;
            }
            __syncthreads();
        }

        // gh partials: 3 gates x 2 sentences over this lane's 16 columns
        float accq[3][2];
#pragma unroll
        for (int q = 0; q < 3; ++q) { accq[q][0] = 0.f; accq[q][1] = 0.f; }
        float hold[2] = {0.f, 0.f};
        if (t > 0) {
#pragma unroll
            for (int s = 0; s < 2; ++s) {
                hold[s] = hlds[LDSP(s * 512 + j)];
                const int base = s * 640 + 20 * lane;    // = LDSP(s*512+colbase)
#pragma unroll
                for (int c4 = 0; c4 < 4; ++c4) {
                    float4 hv = *(const float4*)&hlds[base + c4 * 4];
#pragma unroll
                    for (int q = 0; q < 3; ++q) {
                        accq[q][s] += wreg[q][c4*4+0] * hv.x + wreg[q][c4*4+1] * hv.y
                                    + wreg[q][c4*4+2] * hv.z + wreg[q][c4*4+3] * hv.w;
                    }
                }
            }
#pragma unroll
            for (int q = 0; q < 3; ++q)
#pragma unroll
                for (int s = 0; s < 2; ++s) {
                    float v = accq[q][s];
                    v += __shfl_xor(v, 16, 64);
                    v += __shfl_xor(v, 8, 64);
                    v += __shfl_xor(v, 4, 64);
                    v += __shfl_xor(v, 2, 64);
                    v += __shfl_xor(v, 1, 64);
                    accq[q][s] = v;
                }
        }

        float hn[2];
#pragma unroll
        for (int s = 0; s < 2; ++s) {
            const float rr = sigm(g0[0][s] + accq[0][s] + bhh_q[0]);
            const float zz = sigm(g0[1][s] + accq[1][s] + bhh_q[1]);
            const float nn = tanhf(g0[2][s] + rr * (accq[2][s] + bhh_q[2]));
            hn[s] = (1.f - zz) * nn + zz * hold[s];
        }

        if (lane == 0) {
#pragma unroll
            for (int s = 0; s < 2; ++s) {
                __hip_atomic_store(hstep + (size_t)(t + 1) * 1024 + s * 512 + j, hn[s],
                                   __ATOMIC_RELAXED, __HIP_MEMORY_SCOPE_AGENT);
                if (xout != nullptr)
                    xout[((size_t)s * T + t) * 512 + j] = hn[s];
                if (finout != nullptr && t == T - 1)
                    finout[(size_t)s * fin_ss + j] = hn[s];
            }
        }
        __builtin_amdgcn_s_waitcnt(0);   // this wave's h stores are in the LLC
        __syncthreads();                 // -> all waves' stores are
        if (tid == 0)
            __hip_atomic_store(myflag, (unsigned)(t + 1),
                               __ATOMIC_RELAXED, __HIP_MEMORY_SCOPE_AGENT);
    }
}

// ---------------------------------------------------------------------------
// gi GEMM: out[m][n] = sum_k A[m][k] * W[n][k] + bias[n]; M=512, N=1536, K=512.
// ---------------------------------------------------------------------------
__global__ __launch_bounds__(256, 2) void k_gemm_gi(
    const float* __restrict__ W, const float* __restrict__ bias,
    const float* __restrict__ emb, const int* __restrict__ sentA,
    const int* __restrict__ sentB, const float* __restrict__ xsrc,
    float* __restrict__ out)
{
    __shared__ float At[32][68];
    __shared__ float Wt[32][68];
    const int tid = threadIdx.x;
    const int n0 = blockIdx.x * 64;
    const int m0 = blockIdx.y * 64;
    const int lrow = tid >> 3, lc4 = tid & 7;

    const float *ar0, *ar1;
    {
        const int ma = m0 + lrow, mb = ma + 32;
        if (emb != nullptr) {
            const int ia = (ma < 256) ? sentA[ma & 255] : sentB[ma & 255];
            const int ib = (mb < 256) ? sentA[mb & 255] : sentB[mb & 255];
            ar0 = emb + (size_t)ia * 512;
            ar1 = emb + (size_t)ib * 512;
        } else {
            ar0 = xsrc + (size_t)ma * 512;
            ar1 = xsrc + (size_t)mb * 512;
        }
    }
    const float* wr0 = W + (size_t)(n0 + lrow) * 512;
    const float* wr1 = wr0 + (size_t)32 * 512;

    const int ty = tid >> 4, tx = tid & 15;
    float acc[4][4];
#pragma unroll
    for (int i = 0; i < 4; ++i)
#pragma unroll
        for (int jj = 0; jj < 4; ++jj) acc[i][jj] = 0.f;

    for (int kk = 0; kk < 512; kk += 32) {
        float4 a0 = *(const float4*)(ar0 + kk + lc4 * 4);
        float4 a1 = *(const float4*)(ar1 + kk + lc4 * 4);
        float4 w0 = *(const float4*)(wr0 + kk + lc4 * 4);
        float4 w1 = *(const float4*)(wr1 + kk + lc4 * 4);
        __syncthreads();
        const int kb = lc4 * 4;
        At[kb+0][lrow] = a0.x; At[kb+1][lrow] = a0.y; At[kb+2][lrow] = a0.z; At[kb+3][lrow] = a0.w;
        At[kb+0][lrow+32] = a1.x; At[kb+1][lrow+32] = a1.y; At[kb+2][lrow+32] = a1.z; At[kb+3][lrow+32] = a1.w;
        Wt[kb+0][lrow] = w0.x; Wt[kb+1][lrow] = w0.y; Wt[kb+2][lrow] = w0.z; Wt[kb+3][lrow] = w0.w;
        Wt[kb+0][lrow+32] = w1.x; Wt[kb+1][lrow+32] = w1.y; Wt[kb+2][lrow+32] = w1.z; Wt[kb+3][lrow+32] = w1.w;
        __syncthreads();
#pragma unroll
        for (int k = 0; k < 32; ++k) {
            float4 av = *(const float4*)&At[k][ty * 4];
            float4 wv = *(const float4*)&Wt[k][tx * 4];
            acc[0][0] += av.x * wv.x; acc[0][1] += av.x * wv.y; acc[0][2] += av.x * wv.z; acc[0][3] += av.x * wv.w;
            acc[1][0] += av.y * wv.x; acc[1][1] += av.y * wv.y; acc[1][2] += av.y * wv.z; acc[1][3] += av.y * wv.w;
            acc[2][0] += av.z * wv.x; acc[2][1] += av.z * wv.y; acc[2][2] += av.z * wv.z; acc[2][3] += av.z * wv.w;
            acc[3][0] += av.w * wv.x; acc[3][1] += av.w * wv.y; acc[3][2] += av.w * wv.z; acc[3][3] += av.w * wv.w;
        }
    }
    float4 b4 = *(const float4*)(bias + n0 + tx * 4);
#pragma unroll
    for (int i = 0; i < 4; ++i) {
        const int m = m0 + ty * 4 + i;
        float4 r;
        r.x = acc[i][0] + b4.x; r.y = acc[i][1] + b4.y;
        r.z = acc[i][2] + b4.z; r.w = acc[i][3] + b4.w;
        *(float4*)(out + (size_t)m * 1536 + n0 + tx * 4) = r;
    }
}

// ---------------------------------------------------------------------------
__global__ __launch_bounds__(256) void k_init(
    const float* __restrict__ Wih2, float* __restrict__ Srow,
    unsigned int* __restrict__ flags)
{
    const int g = blockIdx.x * 256 + threadIdx.x;   // 0..2047
    if (g < 1536) {
        float s = 0.f;
        for (int k = 0; k < 128; ++k) s += Wih2[(size_t)g * 128 + k];
        Srow[g] = s;
    }
    for (int i = g; i < 5 * 512; i += 2048) flags[i] = 0u;
}

// ---------------------------------------------------------------------------
__global__ __launch_bounds__(256) void k_convpool(
    const float* __restrict__ x0, const float* __restrict__ x1,
    const float* __restrict__ cw, const float* __restrict__ cb,
    float* __restrict__ Mmax)
{
    __shared__ float hh[2][512];
    __shared__ float wsh[2][512];
    __shared__ float red[4];
    const int s = blockIdx.x >> 1, o = blockIdx.x & 1;
    const int tid = threadIdx.x;
    for (int i = tid; i < 512; i += 256) {
        hh[0][i] = x0[(size_t)(s * 2 + 1) * 512 + i];
        hh[1][i] = x1[(size_t)(s * 2 + 1) * 512 + i];
        wsh[0][i] = cw[(size_t)(o * 2 + 0) * 512 + i];
        wsh[1][i] = cw[(size_t)(o * 2 + 1) * 512 + i];
    }
    __syncthreads();
    const int p = tid;
    float acc = cb[o];
    const int base = 2 * p - 255;
#pragma unroll 1
    for (int ch = 0; ch < 2; ++ch) {
        for (int k = 0; k < 512; ++k) {
            const int pos = base + k;
            if ((unsigned)pos < 512u) acc += hh[ch][pos] * wsh[ch][k];
        }
    }
    float m = acc;
#pragma unroll
    for (int off = 32; off >= 1; off >>= 1) m = fmaxf(m, __shfl_xor(m, off, 64));
    if ((tid & 63) == 0) red[tid >> 6] = m;
    __syncthreads();
    if (tid == 0)
        Mmax[blockIdx.x] = fmaxf(fmaxf(red[0], red[1]), fmaxf(red[2], red[3]));
}

// ---------------------------------------------------------------------------
__global__ __launch_bounds__(256) void k_head(
    const float* __restrict__ xr2,
    const float* __restrict__ WA, const float* __restrict__ WB,
    const float* __restrict__ b_bi, const float* __restrict__ Wlin,
    const float* __restrict__ blin, float* __restrict__ outp)
{
    __shared__ float hA[512], hB[512];
    __shared__ float red[4];
    const int tid = threadIdx.x;
    for (int i = tid; i < 512; i += 256) {
        hA[i] = xr2[512 + i];
        hB[i] = xr2[3 * 512 + i];
    }
    __syncthreads();
    float acc = b_bi[tid];
    for (int jj = 0; jj < 512; ++jj) {
        const float a = hA[jj], b = hB[jj];
        acc += (a * b) * WA[jj * 256 + tid] + fabsf(a - b) * WB[jj * 256 + tid];
    }
    float v = tanhf(acc) * Wlin[tid];
#pragma unroll
    for (int off = 32; off >= 1; off >>= 1) v += __shfl_xor(v, off, 64);
    if ((tid & 63) == 0) red[tid >> 6] = v;
    __syncthreads();
    if (tid == 0) {
        const float ssum = red[0] + red[1] + red[2] + red[3] + blin[0];
        outp[0] = 1.f / (1.f + expf(-ssum));
    }
}

// ---------------------------------------------------------------------------
extern "C" void kernel_launch(void* const* d_in, const int* in_sizes, int n_in,
                              void* d_out, int out_size, void* d_ws, size_t ws_size,
                              hipStream_t stream)
{
    const int*   sentA = (const int*)d_in[0];
    const int*   sentB = (const int*)d_in[1];
    const float* emb   = (const float*)d_in[2];
    const float* Wih1  = (const float*)d_in[3];   // [2][1536][512]
    const float* Whh1  = (const float*)d_in[4];   // [2][1536][512]
    const float* bih1  = (const float*)d_in[5];   // [2][1536]
    const float* bhh1  = (const float*)d_in[6];   // [2][1536]
    const float* convw = (const float*)d_in[7];   // [2][2][512]
    const float* convb = (const float*)d_in[8];   // [2]
    const float* Wih2  = (const float*)d_in[9];   // [1536][128]
    const float* Whh2  = (const float*)d_in[10];  // [1536][512]
    const float* bih2  = (const float*)d_in[11];  // [1536]
    const float* bhh2  = (const float*)d_in[12];  // [1536]
    const float* WA    = (const float*)d_in[13];  // [512][256]
    const float* WB    = (const float*)d_in[14];  // [512][256]
    const float* b_bi  = (const float*)d_in[15];  // [256]
    const float* Wlin  = (const float*)d_in[16];  // [1][256]
    const float* blin  = (const float*)d_in[17];  // [1]

    float* ws = (float*)d_ws;
    size_t off = 0;
    float* gi_buf = ws + off; off += 786432;          // [2][256][1536]
    float* xout0  = ws + off; off += 262144;          // e1 L0 outputs [2][256][512]
    float* e2x    = ws + off; off += 2048;            // epoch2 input [2][2][512]
    float* xo20   = ws + off; off += 2048;
    float* xo21   = ws + off; off += 2048;
    float* xr2b   = ws + off; off += 2048;
    float* Mmax   = ws + off; off += 16;
    float* Srow   = ws + off; off += 1536;
    float* hs0    = ws + off; off += 257 * 1024;      // hstep chain0
    float* hs1    = ws + off; off += 257 * 1024;      // hstep chain1
    float* hs2    = ws + off; off += 3 * 1024;
    float* hs3    = ws + off; off += 3 * 1024;
    float* hs4    = ws + off; off += 3 * 1024;
    unsigned int* flags = (unsigned int*)(ws + off); off += 5 * 512;

    const size_t WSTRIDE = (size_t)1536 * 512;

    k_init<<<8, 256, 0, stream>>>(Wih2, Srow, flags);

    // epoch 1, layer 0
    k_gemm_gi<<<dim3(24, 8), 256, 0, stream>>>(Wih1, bih1, emb, sentA, sentB, nullptr, gi_buf);
    k_chain4<<<32, 512, 0, stream>>>(Whh1, bhh1, gi_buf,
                                     nullptr, nullptr, nullptr, nullptr, nullptr,
                                     xout0, e2x, 1024, hs0, flags + 0 * 512, 256, 0);
    // epoch 1, layer 1
    k_gemm_gi<<<dim3(24, 8), 256, 0, stream>>>(Wih1 + WSTRIDE, bih1 + 1536,
                                               nullptr, nullptr, nullptr, xout0, gi_buf);
    k_chain4<<<32, 512, 0, stream>>>(Whh1 + WSTRIDE, bhh1 + 1536, gi_buf,
                                     nullptr, nullptr, nullptr, nullptr, nullptr,
                                     nullptr, e2x + 512, 1024, hs1, flags + 1 * 512, 256, 0);
    // epoch 2, layer 0 (T=2)
    k_chain4<<<32, 512, 0, stream>>>(Whh1, bhh1, nullptr,
                                     Wih1, bih1, e2x, nullptr, nullptr,
                                     xo20, nullptr, 0, hs2, flags + 2 * 512, 2, 1);
    // epoch 2, layer 1 (T=2)
    k_chain4<<<32, 512, 0, stream>>>(Whh1 + WSTRIDE, bhh1 + 1536, nullptr,
                                     Wih1 + WSTRIDE, bih1 + 1536, xo20, nullptr, nullptr,
                                     xo21, nullptr, 0, hs3, flags + 3 * 512, 2, 1);
    // conv + degenerate max pool
    k_convpool<<<4, 256, 0, stream>>>(xo20, xo21, convw, convb, Mmax);
    // rnn_second (T=2)
    k_chain4<<<32, 512, 0, stream>>>(Whh2, bhh2, nullptr,
                                     nullptr, bih2, nullptr, Mmax, Srow,
                                     xr2b, nullptr, 0, hs4, flags + 4 * 512, 2, 2);
    // similarity head
    k_head<<<1, 256, 0, stream>>>(xr2b, WA, WB, b_bi, Wlin, blin, (float*)d_out);
}